// Round 7
// baseline (343.420 us; speedup 1.0000x reference)
//
#include <hip/hip_runtime.h>

#define NGRAPH 1000
#define P      100
#define EPG    1200
#define INF    16
#define HID    64
#define NOUT   5

// r25 = r24 plane design with the two governing parameters fixed:
//  - SPILL ROOT CAUSE (r20/r21/r24 all WRITE 40-47MB vs r18/r19 47KB):
//    __launch_bounds__(256,4) caps the unified VGPR+AGPR file at 128/wave
//    (4 waves/SIMD x 512-reg pool). 8 persistent short8 adjacency frags +
//    acc[7] + temps ~ 160 regs -> allocator spills ~160B/thread; 125
//    blocks/XCD x 40KB scratch >> 4MB L2 -> HBM. FIX: (256,3) -> cap ~170.
//    LDS is 51.7KB -> 3 blocks/CU regardless, so occupancy unchanged.
//  - BANK PATHOLOGY (r24 conflicts 1.67e7): FSTR=96 shorts = 48 dwords
//    == 16 mod 32 -> all rows alias 2 banks. FIX: FSTR=128 + bijective
//    4-bit XOR swizzle col ^= (row&15)<<3 (flips bits 3..6, col'<128):
//      * W-phase b128: 16 rows -> 16 distinct 16B slots -> 2-way (free).
//      * prop u16: 4 slot-groups x 4 bank-offsets -> 2-way (free).
//  - Everything else identical to the PASSING r24: dual bf16 planes
//    (zero repack VALU), in-kernel adjacency build (cnt aliases plane 0,
//    extracted to regs behind a barrier), RNE hi/lo numerics, no abuild.
// HARD RULES: no runtime-indexed local arrays / pointers-to-locals;
// verified MFMA lane maps (A: row=l&15,k=8q+j; B: col=l&15,k=8q+j;
// D: col=l&15,row=4q+r) unchanged.

#define FSTR   128
#define T1OFF  64
#define T2OFF  80

#define RK1 64
#define RK2 208
#define L1HI 0
#define L1LO 4096
#define L2HI 8192
#define L2LO 21504
#define L3HI 34816
#define L3LO 48128

typedef short short8 __attribute__((ext_vector_type(8)));
typedef float f32x4  __attribute__((ext_vector_type(4)));

// bijective per-row swizzle: flips col bits 3..6 by node bits 0..3
__device__ __forceinline__ int swf(int row, int col) {
    return row * FSTR + (col ^ ((row & 15) << 3));
}

// RNE split of fp32 into (bf16hi<<16)|bf16lo
__device__ __forceinline__ unsigned packsplit(float x) {
    unsigned u  = __float_as_uint(x);
    unsigned hi = (u + 0x7fffu + ((u >> 16) & 1u)) >> 16;
    float r = x - __uint_as_float(hi << 16);
    unsigned v  = __float_as_uint(r);
    unsigned lo = (v + 0x7fffu + ((v >> 16) & 1u)) >> 16;
    return (hi << 16) | (lo & 0xffffu);
}

__device__ __forceinline__ float up2(short h, short l) {
    return __uint_as_float(((unsigned)(unsigned short)h) << 16) +
           __uint_as_float(((unsigned)(unsigned short)l) << 16);
}

// ---- W split/transpose pre-kernel (unchanged tables) ----
__global__ __launch_bounds__(256) void wprep(
    const float* __restrict__ W1, const float* __restrict__ W2,
    const float* __restrict__ W3, short* __restrict__ wt)
{
    const int i0 = blockIdx.x * blockDim.x + threadIdx.x;
    const int stride = gridDim.x * blockDim.x;
    for (int e = i0; e < HID * RK1; e += stride) {
        int c = e / RK1, r = e % RK1;
        float v = (r < 3 * INF) ? W1[r * HID + c] : 0.f;
        unsigned p = packsplit(v);
        wt[L1HI + e] = (short)(p >> 16);
        wt[L1LO + e] = (short)(p & 0xffffu);
    }
    for (int e = i0; e < HID * RK2; e += stride) {
        int c = e / RK2, r = e % RK2;
        float v2 = (r < 3 * HID) ? W2[r * HID + c] : 0.f;
        float v3 = (r < 3 * HID) ? W3[r * HID + c] : 0.f;
        unsigned p2 = packsplit(v2), p3 = packsplit(v3);
        wt[L2HI + e] = (short)(p2 >> 16); wt[L2LO + e] = (short)(p2 & 0xffffu);
        wt[L3HI + e] = (short)(p3 >> 16); wt[L3LO + e] = (short)(p3 & 0xffffu);
    }
}

// ---- one dense propagation reading the bf16 planes ----
// SECOND=0: T1 = -d^2 (Aint @ src);  SECOND=1: T2 = -2 d^2 (Aint @ src) - Y
template <int SECOND>
__device__ __forceinline__ void dense_prop(
    short* __restrict__ Ahi, short* __restrict__ Alo,
    short8 a00, short8 a01, short8 a02, short8 a03,
    short8 a10, short8 a11, short8 a12, short8 a13,
    bool has2, int srcoff, int dstoff, int ycb,
    int rb0, int rb1, f32x4 dv0, f32x4 dv1, int lane)
{
    const int n16 = lane & 15;
    const int q   = lane >> 4;
    const int kq  = q * 8;
    const int cc  = srcoff + n16;
    f32x4 p0, p1;
    p0[0]=0.f; p0[1]=0.f; p0[2]=0.f; p0[3]=0.f;
    p1[0]=0.f; p1[1]=0.f; p1[2]=0.f; p1[3]=0.f;

#define PROPK(KK, A0, A1) { \
    const int r0 = KK * 32 + kq; \
    short8 bhi, blo; \
    if (KK < 3) { \
        const int i0 = swf(r0 + 0, cc); const int i1 = swf(r0 + 1, cc); \
        const int i2 = swf(r0 + 2, cc); const int i3 = swf(r0 + 3, cc); \
        const int i4 = swf(r0 + 4, cc); const int i5 = swf(r0 + 5, cc); \
        const int i6 = swf(r0 + 6, cc); const int i7 = swf(r0 + 7, cc); \
        bhi[0]=Ahi[i0]; blo[0]=Alo[i0]; bhi[1]=Ahi[i1]; blo[1]=Alo[i1]; \
        bhi[2]=Ahi[i2]; blo[2]=Alo[i2]; bhi[3]=Ahi[i3]; blo[3]=Alo[i3]; \
        bhi[4]=Ahi[i4]; blo[4]=Alo[i4]; bhi[5]=Ahi[i5]; blo[5]=Alo[i5]; \
        bhi[6]=Ahi[i6]; blo[6]=Alo[i6]; bhi[7]=Ahi[i7]; blo[7]=Alo[i7]; \
    } else { \
        const int i0 = swf((r0 + 0 < P) ? r0 + 0 : 0, cc); \
        const int i1 = swf((r0 + 1 < P) ? r0 + 1 : 0, cc); \
        const int i2 = swf((r0 + 2 < P) ? r0 + 2 : 0, cc); \
        const int i3 = swf((r0 + 3 < P) ? r0 + 3 : 0, cc); \
        bhi[0]=Ahi[i0]; blo[0]=Alo[i0]; bhi[1]=Ahi[i1]; blo[1]=Alo[i1]; \
        bhi[2]=Ahi[i2]; blo[2]=Alo[i2]; bhi[3]=Ahi[i3]; blo[3]=Alo[i3]; \
        bhi[4]=0; blo[4]=0; bhi[5]=0; blo[5]=0; \
        bhi[6]=0; blo[6]=0; bhi[7]=0; blo[7]=0; \
    } \
    p0 = __builtin_amdgcn_mfma_f32_16x16x32_bf16(A0, bhi, p0, 0, 0, 0); \
    p0 = __builtin_amdgcn_mfma_f32_16x16x32_bf16(A0, blo, p0, 0, 0, 0); \
    if (has2) { \
        p1 = __builtin_amdgcn_mfma_f32_16x16x32_bf16(A1, bhi, p1, 0, 0, 0); \
        p1 = __builtin_amdgcn_mfma_f32_16x16x32_bf16(A1, blo, p1, 0, 0, 0); \
    } }

    PROPK(0, a00, a10)
    PROPK(1, a01, a11)
    PROPK(2, a02, a12)
    PROPK(3, a03, a13)
#undef PROPK

#pragma unroll
    for (int r = 0; r < 4; r++) {
        const int row = rb0 + q * 4 + r;
        const float d2 = dv0[r] * dv0[r];
        float o;
        if (SECOND) {
            const int yi = swf(row, ycb + n16);
            o = -2.f * d2 * p0[r] - up2(Ahi[yi], Alo[yi]);
        } else o = -d2 * p0[r];
        const int di = swf(row, dstoff + n16);
        const unsigned pp = packsplit(o);
        Ahi[di] = (short)(pp >> 16); Alo[di] = (short)pp;
    }
    if (has2) {
#pragma unroll
        for (int r = 0; r < 4; r++) {
            const int row = rb1 + q * 4 + r;
            if (rb1 != 84 || row >= 96) {            // tile-6 overlap guard
                const float d2 = dv1[r] * dv1[r];
                float o;
                if (SECOND) {
                    const int yi = swf(row, ycb + n16);
                    o = -2.f * d2 * p1[r] - up2(Ahi[yi], Alo[yi]);
                } else o = -d2 * p1[r];
                const int di = swf(row, dstoff + n16);
                const unsigned pp = packsplit(o);
                Ahi[di] = (short)(pp >> 16); Alo[di] = (short)pp;
            }
        }
    }
}

// ---- one ChebConv layer ----
template <int F, int FINAL>
__device__ __forceinline__ void cheb_layer(
    short* __restrict__ Ahi, short* __restrict__ Alo,
    const float* __restrict__ dinv,
    short8 a00, short8 a01, short8 a02, short8 a03,
    short8 a10, short8 a11, short8 a12, short8 a13, bool has2,
    const short* __restrict__ whi, const short* __restrict__ wlo,
    const float* __restrict__ bias,
    int tid, int rb0, int rb1, f32x4 dv0, f32x4 dv1)
{
    const int RK   = 3 * F + 16;
    const int lane = tid & 63;
    const int wv   = tid >> 6;
    const int n16  = lane & 15;
    const int q    = lane >> 4;
    const int ncol = (wv << 4) + n16;

    f32x4 acc[7];
#pragma unroll
    for (int t = 0; t < 7; t++) { acc[t][0]=0.f; acc[t][1]=0.f; acc[t][2]=0.f; acc[t][3]=0.f; }

    for (int cb = 0; cb < F; cb += 16) {
        dense_prop<0>(Ahi, Alo, a00,a01,a02,a03, a10,a11,a12,a13, has2,
                      cb,    T1OFF, 0,  rb0, rb1, dv0, dv1, lane);
        __syncthreads();
        dense_prop<1>(Ahi, Alo, a00,a01,a02,a03, a10,a11,a12,a13, has2,
                      T1OFF, T2OFF, cb, rb0, rb1, dv0, dv1, lane);
        __syncthreads();

        // W partial: chunk K-layout [Y16 | T1_16 | T2_16 | zero16], 2 K-steps
#pragma unroll
        for (int ks = 0; ks < 2; ks++) {
            int wr, aoff;
            if (ks == 0) {
                wr   = (q == 0) ? cb : (q == 1) ? cb + 8 : (q == 2) ? F + cb : F + cb + 8;
                aoff = (q == 0) ? cb : (q == 1) ? cb + 8 : (q == 2) ? T1OFF  : T1OFF + 8;
            } else {
                wr   = (q == 0) ? 2*F + cb : (q == 1) ? 2*F + cb + 8 : (q == 2) ? 3*F : 3*F + 8;
                aoff = (q == 0) ? T2OFF    : (q == 1) ? T2OFF + 8    : (q == 2) ? T1OFF : T1OFF + 8;
            }
            const short8 bhi = *(const short8*)&whi[ncol * RK + wr];
            const short8 blo = *(const short8*)&wlo[ncol * RK + wr];
#pragma unroll
            for (int t = 0; t < 7; t++) {
                const int row = ((t < 6) ? t * 16 : 84) + n16;
                const int ax  = swf(row, aoff);            // 16B-aligned slot
                const short8 ahi = *(const short8*)&Ahi[ax];
                const short8 alo = *(const short8*)&Alo[ax];
                acc[t] = __builtin_amdgcn_mfma_f32_16x16x32_bf16(ahi, bhi, acc[t], 0, 0, 0);
                acc[t] = __builtin_amdgcn_mfma_f32_16x16x32_bf16(ahi, blo, acc[t], 0, 0, 0);
                acc[t] = __builtin_amdgcn_mfma_f32_16x16x32_bf16(alo, bhi, acc[t], 0, 0, 0);
            }
        }
        __syncthreads();
    }

    // Epilogue (D: col=lane&15, row=4*(lane>>4)+reg; tile 6 -> rows 84..99)
    const float bcol = bias[ncol];
#pragma unroll
    for (int t = 0; t < 7; t++) {
        const int rbase = ((t < 6) ? t * 16 : 84) + q * 4;
#pragma unroll
        for (int r = 0; r < 4; r++) {
            const int row = rbase + r;
            if (t < 6 || row >= 96) {
                const float dn = dinv[row];
                const float v = acc[t][r];
                float o;
                if (FINAL) o = fmaxf(v * (1.0f / dn) + bcol, 0.f);
                else       o = fmaxf(v + bcol * dn, 0.f);
                const int oi = swf(row, ncol);
                const unsigned pp = packsplit(o);
                Ahi[oi] = (short)(pp >> 16); Alo[oi] = (short)pp;
            }
        }
    }
    __syncthreads();
}

__global__ __launch_bounds__(256, 3) void gnn_kernel(
    const float* __restrict__ feat,
    const int* __restrict__ src, const int* __restrict__ dst,
    const float* __restrict__ b1, const float* __restrict__ b2,
    const float* __restrict__ b3,
    const float* __restrict__ Wfc, const float* __restrict__ bfc,
    const short* __restrict__ wt,
    float* __restrict__ out)
{
    // planes region (51,200 B); first 25,600 B doubles as adjacency counts
    __shared__ __align__(16) unsigned ldsu[12800];
    __shared__ float meta[128];                    // dinv[100] + pool[20]
    short* Ahi = (short*)ldsu;                     // 12800 shorts
    short* Alo = (short*)ldsu + 12800;             // 12800 shorts
    unsigned* cnt = ldsu;                          // 6400 u32 (build phase)

    const int g = blockIdx.x;
    const int tid = threadIdx.x;
    const int base = g * P;
    const int* srcg = src + g * EPG;
    const int* dstg = dst + g * EPG;

    // ---- phase A: zero counts + degrees ----
    int* deg = (int*)meta;
    for (int i = tid; i < 6400; i += 256) cnt[i] = 0u;
    for (int i = tid; i < P; i += 256) deg[i] = 0;
    __syncthreads();
    // ---- phase B: single edge pass (degree + dense counts) ----
    for (int e = tid; e < EPG; e += 256) {
        int s = srcg[e] - base;
        int d = dstg[e] - base;
        atomicAdd(&deg[d], 1);
        atomicAdd(&cnt[d * 64 + (s >> 1)], 1u << ((s & 1) * 16));
    }
    __syncthreads();
    // ---- phase C: dinv + adjacency frag extraction (cnt -> registers) ----
    for (int i = tid; i < P; i += 256) {
        int dg = deg[i];
        meta[i] = rsqrtf((float)(dg > 1 ? dg : 1));
    }
    const int lane = tid & 63, wv = tid >> 6, q = lane >> 4, n16 = lane & 15;
    const int rb0 = wv * 16;
    const int t2i = wv + 4;
    const int rb1 = (t2i >= 6) ? 84 : t2i * 16;
    const bool has2 = (wv < 3);
    const int arow0 = rb0 + n16;
    const int arow1 = (has2 ? rb1 : rb0) + n16;
    short8 a00, a01, a02, a03, a10, a11, a12, a13;
#define MKA(VAR, AR, KK) { \
    const unsigned w0 = cnt[(AR) * 64 + (KK) * 16 + q * 4 + 0]; \
    const unsigned w1 = cnt[(AR) * 64 + (KK) * 16 + q * 4 + 1]; \
    const unsigned w2 = cnt[(AR) * 64 + (KK) * 16 + q * 4 + 2]; \
    const unsigned w3 = cnt[(AR) * 64 + (KK) * 16 + q * 4 + 3]; \
    short8 t; \
    t[0] = (short)(__float_as_uint((float)(w0 & 0xffffu)) >> 16); \
    t[1] = (short)(__float_as_uint((float)(w0 >> 16))     >> 16); \
    t[2] = (short)(__float_as_uint((float)(w1 & 0xffffu)) >> 16); \
    t[3] = (short)(__float_as_uint((float)(w1 >> 16))     >> 16); \
    t[4] = (short)(__float_as_uint((float)(w2 & 0xffffu)) >> 16); \
    t[5] = (short)(__float_as_uint((float)(w2 >> 16))     >> 16); \
    t[6] = (short)(__float_as_uint((float)(w3 & 0xffffu)) >> 16); \
    t[7] = (short)(__float_as_uint((float)(w3 >> 16))     >> 16); \
    VAR = t; }
    MKA(a00, arow0, 0)  MKA(a01, arow0, 1)  MKA(a02, arow0, 2)  MKA(a03, arow0, 3)
    MKA(a10, arow1, 0)  MKA(a11, arow1, 1)  MKA(a12, arow1, 2)  MKA(a13, arow1, 3)
#undef MKA
    __syncthreads();   // extraction complete before planes overwrite cnt

    // ---- phase D: dinv regs + feat load prescaled into planes ----
    f32x4 dv0, dv1;
#pragma unroll
    for (int r = 0; r < 4; r++) {
        dv0[r] = meta[rb0 + q * 4 + r];
        dv1[r] = meta[(has2 ? rb1 : rb0) + q * 4 + r];
    }
    for (int i = tid; i < P * INF / 4; i += 256) {
        int n = i >> 2, f0 = (i & 3) * 4;
        float4 v = *(const float4*)&feat[(size_t)base * INF + i * 4];
        float dn = meta[n];
        unsigned p0 = packsplit(v.x * dn), p1 = packsplit(v.y * dn);
        unsigned p2 = packsplit(v.z * dn), p3 = packsplit(v.w * dn);
        const int bi = swf(n, f0);                 // 4-aligned short index
        *(unsigned*)&Ahi[bi]     = (p0 >> 16) | (p1 & 0xffff0000u);
        *(unsigned*)&Ahi[bi + 2] = (p2 >> 16) | (p3 & 0xffff0000u);
        *(unsigned*)&Alo[bi]     = (p0 & 0xffffu) | (p1 << 16);
        *(unsigned*)&Alo[bi + 2] = (p2 & 0xffffu) | (p3 << 16);
    }
    __syncthreads();

    cheb_layer<INF, 0>(Ahi, Alo, meta, a00,a01,a02,a03, a10,a11,a12,a13, has2,
                       wt + L1HI, wt + L1LO, b1, tid, rb0, rb1, dv0, dv1);
    cheb_layer<HID, 0>(Ahi, Alo, meta, a00,a01,a02,a03, a10,a11,a12,a13, has2,
                       wt + L2HI, wt + L2LO, b2, tid, rb0, rb1, dv0, dv1);
    cheb_layer<HID, 1>(Ahi, Alo, meta, a00,a01,a02,a03, a10,a11,a12,a13, has2,
                       wt + L3HI, wt + L3LO, b3, tid, rb0, rb1, dv0, dv1);

    // ---- mean pool + FC: per-wave column sums -> partial FC -> shuffle ----
    {
        const int l = tid & 63, w = tid >> 6;
        float s = 0.f;
        for (int n = w; n < P; n += 4) {
            const int ii = swf(n, l);
            s += up2(Ahi[ii], Alo[ii]);
        }
        float o0 = s * Wfc[l * NOUT + 0];
        float o1 = s * Wfc[l * NOUT + 1];
        float o2 = s * Wfc[l * NOUT + 2];
        float o3 = s * Wfc[l * NOUT + 3];
        float o4 = s * Wfc[l * NOUT + 4];
#pragma unroll
        for (int d = 1; d < 64; d <<= 1) {
            o0 += __shfl_xor(o0, d);
            o1 += __shfl_xor(o1, d);
            o2 += __shfl_xor(o2, d);
            o3 += __shfl_xor(o3, d);
            o4 += __shfl_xor(o4, d);
        }
        if (l == 0) {
            meta[100 + w * NOUT + 0] = o0;
            meta[100 + w * NOUT + 1] = o1;
            meta[100 + w * NOUT + 2] = o2;
            meta[100 + w * NOUT + 3] = o3;
            meta[100 + w * NOUT + 4] = o4;
        }
    }
    __syncthreads();
    if (tid < NOUT) {
        float o = meta[100 + tid] + meta[105 + tid] + meta[110 + tid] + meta[115 + tid];
        out[g * NOUT + tid] = bfc[tid] + o * (1.0f / P);
    }
}

extern "C" void kernel_launch(void* const* d_in, const int* in_sizes, int n_in,
                              void* d_out, int out_size, void* d_ws, size_t ws_size,
                              hipStream_t stream)
{
    const float* feat = (const float*)d_in[0];
    const int*   src  = (const int*)d_in[1];
    const int*   dst  = (const int*)d_in[2];
    const float* W1  = (const float*)d_in[5];
    const float* b1  = (const float*)d_in[6];
    const float* W2  = (const float*)d_in[7];
    const float* b2  = (const float*)d_in[8];
    const float* W3  = (const float*)d_in[9];
    const float* b3  = (const float*)d_in[10];
    const float* Wfc = (const float*)d_in[11];
    const float* bfc = (const float*)d_in[12];
    float* out = (float*)d_out;

    short* wt = (short*)d_ws;                   // 122,880 B only

    wprep<<<64, 256, 0, stream>>>(W1, W2, W3, wt);
    gnn_kernel<<<NGRAPH, 256, 0, stream>>>(feat, src, dst,
                                           b1, b2, b3, Wfc, bfc, wt, out);
}

// Round 8
// 258.647 us; speedup vs baseline: 1.3278x; 1.3278x over previous
//
#include <hip/hip_runtime.h>

#define NGRAPH 1000
#define P      100
#define EPG    1200
#define INF    16
#define HID    64
#define NOUT   5

// r26 = r19 register discipline (adjacency frags loaded FRESH from global
// inside each prop; NO vector state live across barriers) + packed-u32
// activations + bank-engineered swizzle.
//  - SPILL LAW (6 rounds): persistent short8 frags across layers => 40-93MB
//    scratch (r20/r21/r24/r25); transient per-prop global loads => 47KB
//    (r18/r19, VGPR 64). abuild restored; aint L2-resident (3.2MB/XCD).
//  - Packed u32 = (bf16hi<<16)|bf16lo (r20-verified numerics). Fragments via
//    v_perm pairs: 8 VALU/frag vs r19's 40 bsplit (r19 VALUBusy 55%).
//  - swf: col ^= ((row>>3)&1)<<4 | ((row>>1)&3)<<2  (=0 mod 4, b128-safe):
//      prop b32 reads: q&1 splits halves -> uniform 2/bank (free, m136)
//      prop/epilogue writes + Y reads: 2-way (free)
//      W-phase 2x b128: uniform 8/bank = b128 floor (conflict-free)
//    NOTE: second b128 must use swf(row, aoff+4) (mid-bits break xp+4).
//  - LDS: Ap 100x96 u32 = 38,400B + meta 512B -> 4 blocks/CU, bounds (256,4).
// HARD RULES: no pointers-to-locals, no runtime-indexed local arrays,
// no cross-barrier vector state; verified MFMA lane maps unchanged
// (A: row=l&15,k=8q+j; B: col=l&15,k=8q+j; D: col=l&15,row=4q+r).

#define ASTR   96
#define T1OFF  64
#define T2OFF  80

#define AINT_K  128
#define AINT_SZ (P * AINT_K)

#define RK1 64
#define RK2 208
#define L1HI 0
#define L1LO 4096
#define L2HI 8192
#define L2LO 21504
#define L3HI 34816
#define L3LO 48128
#define WT_SHORTS 61440

typedef short short8 __attribute__((ext_vector_type(8)));
typedef float f32x4  __attribute__((ext_vector_type(4)));
typedef int   int4v  __attribute__((ext_vector_type(4)));

// swizzle: flips col bits 2..4 by row bits; 0 mod 4 -> 4-dword contiguity ok
__device__ __forceinline__ int swf(int row, int col) {
    return row * ASTR +
           (col ^ ((((row >> 3) & 1) << 4) | (((row >> 1) & 3) << 2)));
}

// RNE split of fp32 into (bf16hi<<16)|bf16lo
__device__ __forceinline__ unsigned packsplit(float x) {
    unsigned u  = __float_as_uint(x);
    unsigned hi = (u + 0x7fffu + ((u >> 16) & 1u)) >> 16;
    float r = x - __uint_as_float(hi << 16);
    unsigned v  = __float_as_uint(r);
    unsigned lo = (v + 0x7fffu + ((v >> 16) & 1u)) >> 16;
    return (hi << 16) | (lo & 0xffffu);
}

__device__ __forceinline__ float unpack(unsigned p) {
    return __uint_as_float(p & 0xffff0000u) + __uint_as_float(p << 16);
}

// v_perm selectors (r20 hardware-verified): sel 0-3 from S1(2nd), 4-7 from S0
#define PSEL_HI 0x07060302u
#define PSEL_LO 0x05040100u

// ---- W split/transpose pre-kernel ----
__global__ __launch_bounds__(256) void wprep(
    const float* __restrict__ W1, const float* __restrict__ W2,
    const float* __restrict__ W3, short* __restrict__ wt)
{
    const int i0 = blockIdx.x * blockDim.x + threadIdx.x;
    const int stride = gridDim.x * blockDim.x;
    for (int e = i0; e < HID * RK1; e += stride) {
        int c = e / RK1, r = e % RK1;
        float v = (r < 3 * INF) ? W1[r * HID + c] : 0.f;
        unsigned p = packsplit(v);
        wt[L1HI + e] = (short)(p >> 16);
        wt[L1LO + e] = (short)(p & 0xffffu);
    }
    for (int e = i0; e < HID * RK2; e += stride) {
        int c = e / RK2, r = e % RK2;
        float v2 = (r < 3 * HID) ? W2[r * HID + c] : 0.f;
        float v3 = (r < 3 * HID) ? W3[r * HID + c] : 0.f;
        unsigned p2 = packsplit(v2), p3 = packsplit(v3);
        wt[L2HI + e] = (short)(p2 >> 16); wt[L2LO + e] = (short)(p2 & 0xffffu);
        wt[L3HI + e] = (short)(p3 >> 16); wt[L3LO + e] = (short)(p3 & 0xffffu);
    }
}

// ---- per-graph dense adjacency build (r19 verbatim) ----
__global__ __launch_bounds__(256) void abuild(
    const int* __restrict__ src, const int* __restrict__ dst,
    short* __restrict__ aint)
{
    __shared__ unsigned int cnt[AINT_SZ / 2];     // 25,600 B
    const int g = blockIdx.x, tid = threadIdx.x, base = g * P;
    for (int i = tid; i < AINT_SZ / 2; i += 256) cnt[i] = 0u;
    __syncthreads();
    const int* srcg = src + g * EPG;
    const int* dstg = dst + g * EPG;
    for (int e = tid; e < EPG; e += 256) {
        int s = srcg[e] - base;
        int d = dstg[e] - base;
        int idx = d * AINT_K + s;
        atomicAdd(&cnt[idx >> 1], 1u << ((idx & 1) * 16));
    }
    __syncthreads();
    unsigned int* outw = (unsigned int*)(aint + (size_t)g * AINT_SZ);
    for (int i = tid; i < AINT_SZ / 2; i += 256) {
        unsigned int u = cnt[i];
        unsigned int b0 = __float_as_uint((float)(u & 0xffffu)) >> 16;
        unsigned int b1 = __float_as_uint((float)(u >> 16)) >> 16;
        outw[i] = b0 | (b1 << 16);
    }
}

// ---- one dense propagation; adjacency loaded fresh per K-quad (r19 law) ----
// SECOND=0: T1 = -d^2 (Aint @ src);  SECOND=1: T2 = -2 d^2 (Aint @ src) - Y
template <int SECOND>
__device__ __forceinline__ void dense_prop(
    unsigned* __restrict__ Ap, const short* __restrict__ aintg,
    int arow0, int arow1, bool has2,
    int srcoff, int dstoff, int ycb,
    int rb0, int rb1, f32x4 dv0, f32x4 dv1, int lane)
{
    const int n16 = lane & 15;
    const int q   = lane >> 4;
    const int kq  = q * 8;
    const int cc  = srcoff + n16;
    f32x4 p0, p1;
    p0[0]=0.f; p0[1]=0.f; p0[2]=0.f; p0[3]=0.f;
    p1[0]=0.f; p1[1]=0.f; p1[2]=0.f; p1[3]=0.f;

#define PROPK(KK) { \
    const short8 a0 = *(const short8*)&aintg[arow0 * AINT_K + KK * 32 + kq]; \
    const short8 a1 = *(const short8*)&aintg[arow1 * AINT_K + KK * 32 + kq]; \
    const int r0 = KK * 32 + kq; \
    const unsigned u0 = Ap[swf((KK < 3 || r0 + 0 < P) ? r0 + 0 : 0, cc)]; \
    const unsigned u1 = Ap[swf((KK < 3 || r0 + 1 < P) ? r0 + 1 : 0, cc)]; \
    const unsigned u2 = Ap[swf((KK < 3 || r0 + 2 < P) ? r0 + 2 : 0, cc)]; \
    const unsigned u3 = Ap[swf((KK < 3 || r0 + 3 < P) ? r0 + 3 : 0, cc)]; \
    const unsigned u4 = Ap[swf((KK < 3 || r0 + 4 < P) ? r0 + 4 : 0, cc)]; \
    const unsigned u5 = Ap[swf((KK < 3 || r0 + 5 < P) ? r0 + 5 : 0, cc)]; \
    const unsigned u6 = Ap[swf((KK < 3 || r0 + 6 < P) ? r0 + 6 : 0, cc)]; \
    const unsigned u7 = Ap[swf((KK < 3 || r0 + 7 < P) ? r0 + 7 : 0, cc)]; \
    int4v hh, ll; \
    hh[0] = (int)__builtin_amdgcn_perm(u1, u0, PSEL_HI); \
    hh[1] = (int)__builtin_amdgcn_perm(u3, u2, PSEL_HI); \
    hh[2] = (int)__builtin_amdgcn_perm(u5, u4, PSEL_HI); \
    hh[3] = (int)__builtin_amdgcn_perm(u7, u6, PSEL_HI); \
    ll[0] = (int)__builtin_amdgcn_perm(u1, u0, PSEL_LO); \
    ll[1] = (int)__builtin_amdgcn_perm(u3, u2, PSEL_LO); \
    ll[2] = (int)__builtin_amdgcn_perm(u5, u4, PSEL_LO); \
    ll[3] = (int)__builtin_amdgcn_perm(u7, u6, PSEL_LO); \
    const short8 bhi = __builtin_bit_cast(short8, hh); \
    const short8 blo = __builtin_bit_cast(short8, ll); \
    p0 = __builtin_amdgcn_mfma_f32_16x16x32_bf16(a0, bhi, p0, 0, 0, 0); \
    p0 = __builtin_amdgcn_mfma_f32_16x16x32_bf16(a0, blo, p0, 0, 0, 0); \
    if (has2) { \
        p1 = __builtin_amdgcn_mfma_f32_16x16x32_bf16(a1, bhi, p1, 0, 0, 0); \
        p1 = __builtin_amdgcn_mfma_f32_16x16x32_bf16(a1, blo, p1, 0, 0, 0); \
    } }

    PROPK(0)
    PROPK(1)
    PROPK(2)
    PROPK(3)
#undef PROPK

#pragma unroll
    for (int r = 0; r < 4; r++) {
        const int row = rb0 + q * 4 + r;
        const float d2 = dv0[r] * dv0[r];
        float o;
        if (SECOND) o = -2.f * d2 * p0[r] - unpack(Ap[swf(row, ycb + n16)]);
        else        o = -d2 * p0[r];
        Ap[swf(row, dstoff + n16)] = packsplit(o);
    }
    if (has2) {
#pragma unroll
        for (int r = 0; r < 4; r++) {
            const int row = rb1 + q * 4 + r;
            if (rb1 != 84 || row >= 96) {            // tile-6 overlap guard
                const float d2 = dv1[r] * dv1[r];
                float o;
                if (SECOND) o = -2.f * d2 * p1[r] - unpack(Ap[swf(row, ycb + n16)]);
                else        o = -d2 * p1[r];
                Ap[swf(row, dstoff + n16)] = packsplit(o);
            }
        }
    }
}

// ---- one ChebConv layer ----
template <int F, int FINAL>
__device__ __forceinline__ void cheb_layer(
    unsigned* __restrict__ Ap, const float* __restrict__ dinv,
    const short* __restrict__ aintg, int arow0, int arow1, bool has2,
    const short* __restrict__ whi, const short* __restrict__ wlo,
    const float* __restrict__ bias,
    int tid, int rb0, int rb1, f32x4 dv0, f32x4 dv1)
{
    const int RK   = 3 * F + 16;
    const int lane = tid & 63;
    const int wv   = tid >> 6;
    const int n16  = lane & 15;
    const int q    = lane >> 4;
    const int ncol = (wv << 4) + n16;

    f32x4 acc[7];
#pragma unroll
    for (int t = 0; t < 7; t++) { acc[t][0]=0.f; acc[t][1]=0.f; acc[t][2]=0.f; acc[t][3]=0.f; }

    for (int cb = 0; cb < F; cb += 16) {
        dense_prop<0>(Ap, aintg, arow0, arow1, has2,
                      cb,    T1OFF, 0,  rb0, rb1, dv0, dv1, lane);
        __syncthreads();
        dense_prop<1>(Ap, aintg, arow0, arow1, has2,
                      T1OFF, T2OFF, cb, rb0, rb1, dv0, dv1, lane);
        __syncthreads();

        // W partial: chunk K-layout [Y16 | T1_16 | T2_16 | zero16], 2 K-steps
#pragma unroll
        for (int ks = 0; ks < 2; ks++) {
            int wr, aoff;
            if (ks == 0) {
                wr   = (q == 0) ? cb : (q == 1) ? cb + 8 : (q == 2) ? F + cb : F + cb + 8;
                aoff = (q == 0) ? cb : (q == 1) ? cb + 8 : (q == 2) ? T1OFF  : T1OFF + 8;
            } else {
                wr   = (q == 0) ? 2*F + cb : (q == 1) ? 2*F + cb + 8 : (q == 2) ? 3*F : 3*F + 8;
                aoff = (q == 0) ? T2OFF    : (q == 1) ? T2OFF + 8    : (q == 2) ? T1OFF : T1OFF + 8;
            }
            const short8 bhi = *(const short8*)&whi[ncol * RK + wr];
            const short8 blo = *(const short8*)&wlo[ncol * RK + wr];
#pragma unroll
            for (int t = 0; t < 7; t++) {
                const int row = ((t < 6) ? t * 16 : 84) + n16;
                const int4v w0 = *(const int4v*)&Ap[swf(row, aoff)];
                const int4v w1 = *(const int4v*)&Ap[swf(row, aoff + 4)];
                int4v hh, ll;
                hh[0] = (int)__builtin_amdgcn_perm((unsigned)w0[1], (unsigned)w0[0], PSEL_HI);
                hh[1] = (int)__builtin_amdgcn_perm((unsigned)w0[3], (unsigned)w0[2], PSEL_HI);
                hh[2] = (int)__builtin_amdgcn_perm((unsigned)w1[1], (unsigned)w1[0], PSEL_HI);
                hh[3] = (int)__builtin_amdgcn_perm((unsigned)w1[3], (unsigned)w1[2], PSEL_HI);
                ll[0] = (int)__builtin_amdgcn_perm((unsigned)w0[1], (unsigned)w0[0], PSEL_LO);
                ll[1] = (int)__builtin_amdgcn_perm((unsigned)w0[3], (unsigned)w0[2], PSEL_LO);
                ll[2] = (int)__builtin_amdgcn_perm((unsigned)w1[1], (unsigned)w1[0], PSEL_LO);
                ll[3] = (int)__builtin_amdgcn_perm((unsigned)w1[3], (unsigned)w1[2], PSEL_LO);
                const short8 ahi = __builtin_bit_cast(short8, hh);
                const short8 alo = __builtin_bit_cast(short8, ll);
                acc[t] = __builtin_amdgcn_mfma_f32_16x16x32_bf16(ahi, bhi, acc[t], 0, 0, 0);
                acc[t] = __builtin_amdgcn_mfma_f32_16x16x32_bf16(ahi, blo, acc[t], 0, 0, 0);
                acc[t] = __builtin_amdgcn_mfma_f32_16x16x32_bf16(alo, bhi, acc[t], 0, 0, 0);
            }
        }
        __syncthreads();
    }

    // Epilogue (D: col=lane&15, row=4*(lane>>4)+reg; tile 6 -> rows 84..99)
    const float bcol = bias[ncol];
#pragma unroll
    for (int t = 0; t < 7; t++) {
        const int rbase = ((t < 6) ? t * 16 : 84) + q * 4;
#pragma unroll
        for (int r = 0; r < 4; r++) {
            const int row = rbase + r;
            if (t < 6 || row >= 96) {
                const float dn = dinv[row];
                const float v = acc[t][r];
                float o;
                if (FINAL) o = fmaxf(v * (1.0f / dn) + bcol, 0.f);
                else       o = fmaxf(v + bcol * dn, 0.f);
                Ap[swf(row, ncol)] = packsplit(o);
            }
        }
    }
    __syncthreads();
}

__global__ __launch_bounds__(256, 4) void gnn_kernel(
    const float* __restrict__ feat,
    const int* __restrict__ src, const int* __restrict__ dst,
    const float* __restrict__ b1, const float* __restrict__ b2,
    const float* __restrict__ b3,
    const float* __restrict__ Wfc, const float* __restrict__ bfc,
    const short* __restrict__ wt, const short* __restrict__ aint,
    float* __restrict__ out)
{
    __shared__ __align__(16) unsigned Ap[P * ASTR];   // 38,400 B packed hi|lo
    __shared__ float meta[128];                        // dinv[100] + pool[20]

    const int g = blockIdx.x;
    const int tid = threadIdx.x;
    const int base = g * P;
    const int* dstg = dst + g * EPG;

    // ---- degree count ----
    int* deg = (int*)meta;
    for (int i = tid; i < P; i += 256) deg[i] = 0;
    __syncthreads();
    for (int e = tid; e < EPG; e += 256) atomicAdd(&deg[dstg[e] - base], 1);
    __syncthreads();
    for (int i = tid; i < P; i += 256) {
        int dg = deg[i];
        meta[i] = rsqrtf((float)(dg > 1 ? dg : 1));
    }
    __syncthreads();

    // ---- feat load prescaled (Y = dinv*feat), packed ----
    for (int i = tid; i < P * INF / 4; i += 256) {
        int n = i >> 2, f0 = (i & 3) * 4;
        float4 v = *(const float4*)&feat[(size_t)base * INF + i * 4];
        float dn = meta[n];
        int4v pk;
        pk[0] = (int)packsplit(v.x * dn);
        pk[1] = (int)packsplit(v.y * dn);
        pk[2] = (int)packsplit(v.z * dn);
        pk[3] = (int)packsplit(v.w * dn);
        *(int4v*)&Ap[swf(n, f0)] = pk;     // f0 mult of 4, swz mult of 4: ok
    }
    __syncthreads();

    // ---- per-wave tile assignment + dinv regs (scalars only persist) ----
    const int lane = tid & 63, wv = tid >> 6, q = lane >> 4, n16 = lane & 15;
    const int rb0 = wv * 16;
    const int t2i = wv + 4;
    const int rb1 = (t2i >= 6) ? 84 : t2i * 16;
    const bool has2 = (wv < 3);
    f32x4 dv0, dv1;
#pragma unroll
    for (int r = 0; r < 4; r++) {
        dv0[r] = meta[rb0 + q * 4 + r];
        dv1[r] = meta[(has2 ? rb1 : rb0) + q * 4 + r];
    }
    const short* aintg = aint + (size_t)g * AINT_SZ;
    const int arow0 = rb0 + n16;
    const int arow1 = (has2 ? rb1 : rb0) + n16;

    cheb_layer<INF, 0>(Ap, meta, aintg, arow0, arow1, has2,
                       wt + L1HI, wt + L1LO, b1, tid, rb0, rb1, dv0, dv1);
    cheb_layer<HID, 0>(Ap, meta, aintg, arow0, arow1, has2,
                       wt + L2HI, wt + L2LO, b2, tid, rb0, rb1, dv0, dv1);
    cheb_layer<HID, 1>(Ap, meta, aintg, arow0, arow1, has2,
                       wt + L3HI, wt + L3LO, b3, tid, rb0, rb1, dv0, dv1);

    // ---- mean pool + FC: per-wave column sums -> partial FC -> shuffle ----
    {
        const int l = tid & 63, w = tid >> 6;
        float s = 0.f;
        for (int n = w; n < P; n += 4) s += unpack(Ap[swf(n, l)]);
        float o0 = s * Wfc[l * NOUT + 0];
        float o1 = s * Wfc[l * NOUT + 1];
        float o2 = s * Wfc[l * NOUT + 2];
        float o3 = s * Wfc[l * NOUT + 3];
        float o4 = s * Wfc[l * NOUT + 4];
#pragma unroll
        for (int d = 1; d < 64; d <<= 1) {
            o0 += __shfl_xor(o0, d);
            o1 += __shfl_xor(o1, d);
            o2 += __shfl_xor(o2, d);
            o3 += __shfl_xor(o3, d);
            o4 += __shfl_xor(o4, d);
        }
        if (l == 0) {
            meta[100 + w * NOUT + 0] = o0;
            meta[100 + w * NOUT + 1] = o1;
            meta[100 + w * NOUT + 2] = o2;
            meta[100 + w * NOUT + 3] = o3;
            meta[100 + w * NOUT + 4] = o4;
        }
    }
    __syncthreads();
    if (tid < NOUT) {
        float o = meta[100 + tid] + meta[105 + tid] + meta[110 + tid] + meta[115 + tid];
        out[g * NOUT + tid] = bfc[tid] + o * (1.0f / P);
    }
}

extern "C" void kernel_launch(void* const* d_in, const int* in_sizes, int n_in,
                              void* d_out, int out_size, void* d_ws, size_t ws_size,
                              hipStream_t stream)
{
    const float* feat = (const float*)d_in[0];
    const int*   src  = (const int*)d_in[1];
    const int*   dst  = (const int*)d_in[2];
    const float* W1  = (const float*)d_in[5];
    const float* b1  = (const float*)d_in[6];
    const float* W2  = (const float*)d_in[7];
    const float* b2  = (const float*)d_in[8];
    const float* W3  = (const float*)d_in[9];
    const float* b3  = (const float*)d_in[10];
    const float* Wfc = (const float*)d_in[11];
    const float* bfc = (const float*)d_in[12];
    float* out = (float*)d_out;

    short* wt   = (short*)d_ws;                 // 122,880 B
    short* aint = wt + WT_SHORTS;               // + 25,600,000 B

    wprep<<<64, 256, 0, stream>>>(W1, W2, W3, wt);
    abuild<<<NGRAPH, 256, 0, stream>>>(src, dst, aint);
    gnn_kernel<<<NGRAPH, 256, 0, stream>>>(feat, src, dst,
                                           b1, b2, b3, Wfc, bfc, wt, aint, out);
}

// Round 9
// 177.617 us; speedup vs baseline: 1.9335x; 1.4562x over previous
//
#include <hip/hip_runtime.h>

#define NGRAPH 1000
#define P      100
#define EPG    1200
#define INF    16
#define HID    64
#define NOUT   5

// r27 = round-1 r19 EXACT (161.7us total / 82.8us gnn, the session best:
// raw fp32 LDS activations, inline bsplit fragment builds, adjacency loaded
// fresh from global inside each prop — the ONLY codegen-clean lineage across
// 8 rounds; every packed/perm/persistent-frag variant spilled 40-90MB) plus
// ONE format-preserving change:
//  - BANK SWIZZLE: prop reads had bank = 4j + (srcoff+n16) mod 32 — the row
//    term 8q*4 = 0 mod 32, so all 4 K-quads collided on 16 banks (4-way,
//    8.1e6 conflicts in r19). New layout: cols 0..95 data (Y 0..63,
//    T1 64..79, T2 80..95; XOR-closed), dinv/deg at cols 96/97 (unswizzled).
//    swf: col ^= ((s&1)<<4)|((s>>1)<<2), s=(row>>3)&3. In prop s==q -> quads
//    split across bank halves -> uniform 2/bank (free, m136). W-phase float4
//    stays granule-aligned (bits 0..1 untouched); n16 vs n16+8 decollide.
// HARD RULES (8-round law): raw fp32 LDS + bsplit only; no packed u32, no
// v_perm/bit_cast fragment builds, no cross-barrier vector state, no
// pointers-to-locals. Verified MFMA lane maps unchanged.

#define ASTR   100
#define T1OFF  64
#define T2OFF  80
#define DINVC  96
#define DEGC   97

#define AINT_K   128
#define AINT_SZ  (P * AINT_K)

#define RK1    64
#define RK2    208
#define L1HI   0
#define L1LO   4096
#define L2HI   8192
#define L2LO   21504
#define L3HI   34816
#define L3LO   48128
#define WT_SHORTS 61440

typedef short short8 __attribute__((ext_vector_type(8)));
typedef float f32x4  __attribute__((ext_vector_type(4)));

// swizzled index for DATA cols (<96). Meta cols 96..99 accessed directly.
__device__ __forceinline__ int swf(int row, int col) {
    const int s = (row >> 3) & 3;
    return row * ASTR + (col ^ (((s & 1) << 4) | ((s >> 1) << 2)));
}

__device__ __forceinline__ void bsplit(float x, short& h, short& l) {
    unsigned u = __float_as_uint(x);
    h = (short)(u >> 16);
    float hf = __uint_as_float(u & 0xffff0000u);
    l = (short)(__float_as_uint(x - hf) >> 16);
}

// ---- W split/transpose pre-kernel (round-1 verbatim) ----
__global__ __launch_bounds__(256) void wprep(
    const float* __restrict__ W1, const float* __restrict__ W2,
    const float* __restrict__ W3, short* __restrict__ wt)
{
    const int i0 = blockIdx.x * blockDim.x + threadIdx.x;
    const int stride = gridDim.x * blockDim.x;
    for (int e = i0; e < HID * RK1; e += stride) {
        int c = e / RK1, r = e % RK1;
        float v = (r < 3 * INF) ? W1[r * HID + c] : 0.f;
        short h, l; bsplit(v, h, l);
        wt[L1HI + e] = h;
        wt[L1LO + e] = l;
    }
    for (int e = i0; e < HID * RK2; e += stride) {
        int c = e / RK2, r = e % RK2;
        float v2 = (r < 3 * HID) ? W2[r * HID + c] : 0.f;
        float v3 = (r < 3 * HID) ? W3[r * HID + c] : 0.f;
        short h, l;
        bsplit(v2, h, l); wt[L2HI + e]  = h; wt[L2LO + e] = l;
        bsplit(v3, h, l); wt[L3HI + e] = h; wt[L3LO + e] = l;
    }
}

// ---- per-graph dense adjacency build (round-1 verbatim) ----
__global__ __launch_bounds__(256) void abuild(
    const int* __restrict__ src, const int* __restrict__ dst,
    short* __restrict__ aint)
{
    __shared__ unsigned int cnt[AINT_SZ / 2];     // 25,600 B
    const int g = blockIdx.x, tid = threadIdx.x, base = g * P;
    for (int i = tid; i < AINT_SZ / 2; i += 256) cnt[i] = 0u;
    __syncthreads();
    const int* srcg = src + g * EPG;
    const int* dstg = dst + g * EPG;
    for (int e = tid; e < EPG; e += 256) {
        int s = srcg[e] - base;
        int d = dstg[e] - base;
        int idx = d * AINT_K + s;
        atomicAdd(&cnt[idx >> 1], 1u << ((idx & 1) * 16));
    }
    __syncthreads();
    unsigned int* outw = (unsigned int*)(aint + (size_t)g * AINT_SZ);
    for (int i = tid; i < AINT_SZ / 2; i += 256) {
        unsigned int u = cnt[i];
        unsigned int b0 = __float_as_uint((float)(u & 0xffffu)) >> 16;
        unsigned int b1 = __float_as_uint((float)(u >> 16)) >> 16;
        outw[i] = b0 | (b1 << 16);
    }
}

// ---- one dense propagation (round-1 verbatim + swf) ----
// SECOND=0: T1 = -d^2 (Aint @ src);  SECOND=1: T2 = -2 d^2 (Aint @ src) - Y
template <int SECOND>
__device__ __forceinline__ void dense_prop(
    float* __restrict__ A, const short* __restrict__ aintg,
    int arow0, int arow1, bool has2,
    int srcoff, int dstoff, int ycb,
    int rb0, int rb1, f32x4 dv0, f32x4 dv1, int lane)
{
    const int n16 = lane & 15;
    const int q   = lane >> 4;
    const int kq  = q * 8;
    f32x4 p0, p1;
    p0[0]=0.f; p0[1]=0.f; p0[2]=0.f; p0[3]=0.f;
    p1[0]=0.f; p1[1]=0.f; p1[2]=0.f; p1[3]=0.f;
#pragma unroll
    for (int k = 0; k < 4; k++) {
        const short8 a0 = *(const short8*)&aintg[arow0 * AINT_K + k * 32 + kq];
        const short8 a1 = *(const short8*)&aintg[arow1 * AINT_K + k * 32 + kq];
        short8 bhi, blo; short h, l;
#pragma unroll
        for (int j = 0; j < 8; j++) {
            int row = k * 32 + kq + j;
            if (k == 3) row = (row < P) ? row : 0;   // Aint cols >=100 are 0
            float x = A[swf(row, srcoff + n16)];
            bsplit(x, h, l); bhi[j] = h; blo[j] = l;
        }
        p0 = __builtin_amdgcn_mfma_f32_16x16x32_bf16(a0, bhi, p0, 0, 0, 0);
        p0 = __builtin_amdgcn_mfma_f32_16x16x32_bf16(a0, blo, p0, 0, 0, 0);
        if (has2) {
            p1 = __builtin_amdgcn_mfma_f32_16x16x32_bf16(a1, bhi, p1, 0, 0, 0);
            p1 = __builtin_amdgcn_mfma_f32_16x16x32_bf16(a1, blo, p1, 0, 0, 0);
        }
    }
#pragma unroll
    for (int r = 0; r < 4; r++) {
        const int row = rb0 + q * 4 + r;
        const float d2 = dv0[r] * dv0[r];
        float o;
        if (SECOND) o = -2.f * d2 * p0[r] - A[swf(row, ycb + n16)];
        else        o = -d2 * p0[r];
        A[swf(row, dstoff + n16)] = o;
    }
    if (has2) {
#pragma unroll
        for (int r = 0; r < 4; r++) {
            const int row = rb1 + q * 4 + r;
            if (rb1 != 84 || row >= 96) {            // tile-6 overlap guard
                const float d2 = dv1[r] * dv1[r];
                float o;
                if (SECOND) o = -2.f * d2 * p1[r] - A[swf(row, ycb + n16)];
                else        o = -d2 * p1[r];
                A[swf(row, dstoff + n16)] = o;
            }
        }
    }
}

// ---- one ChebConv layer (round-1 verbatim + swf) ----
template <int F, int FINAL>
__device__ __forceinline__ void cheb_layer(
    float* __restrict__ A, const short* __restrict__ aintg,
    int arow0, int arow1, bool has2,
    const short* __restrict__ whi, const short* __restrict__ wlo,
    const float* __restrict__ bias,
    int tid, int rb0, int rb1, f32x4 dv0, f32x4 dv1)
{
    const int RK   = 3 * F + 16;
    const int lane = tid & 63;
    const int wv   = tid >> 6;
    const int n16  = lane & 15;
    const int q    = lane >> 4;
    const int ncol = (wv << 4) + n16;

    f32x4 acc[7];
#pragma unroll
    for (int t = 0; t < 7; t++) { acc[t][0]=0.f; acc[t][1]=0.f; acc[t][2]=0.f; acc[t][3]=0.f; }

    for (int cb = 0; cb < F; cb += 16) {
        dense_prop<0>(A, aintg, arow0, arow1, has2,
                      cb,    T1OFF, 0,  rb0, rb1, dv0, dv1, lane);
        __syncthreads();
        dense_prop<1>(A, aintg, arow0, arow1, has2,
                      T1OFF, T2OFF, cb, rb0, rb1, dv0, dv1, lane);
        __syncthreads();

        // W partial: chunk K-layout [Y16 | T1_16 | T2_16 | zero16], 2 K-steps
#pragma unroll
        for (int ks = 0; ks < 2; ks++) {
            int wr, aoff;
            if (ks == 0) {
                wr   = (q == 0) ? cb : (q == 1) ? cb + 8 : (q == 2) ? F + cb : F + cb + 8;
                aoff = (q == 0) ? cb : (q == 1) ? cb + 8 : (q == 2) ? T1OFF  : T1OFF + 8;
            } else {
                wr   = (q == 0) ? 2*F + cb : (q == 1) ? 2*F + cb + 8 : (q == 2) ? 3*F : 3*F + 8;
                aoff = (q == 0) ? T2OFF    : (q == 1) ? T2OFF + 8    : (q == 2) ? T1OFF : T1OFF + 8;
            }
            const short8 bhi = *(const short8*)&whi[ncol * RK + wr];
            const short8 blo = *(const short8*)&wlo[ncol * RK + wr];
#pragma unroll
            for (int t = 0; t < 7; t++) {
                const int row = ((t < 6) ? t * 16 : 84) + n16;
                // two granule-swizzled float4 loads (16B-aligned; bits 0..1
                // of the index are untouched by swf)
                const float4 v0 = *(const float4*)&A[swf(row, aoff)];
                const float4 v1 = *(const float4*)&A[swf(row, aoff + 4)];
                short8 ahi, alo; short h, l;
                bsplit(v0.x, h, l); ahi[0] = h; alo[0] = l;
                bsplit(v0.y, h, l); ahi[1] = h; alo[1] = l;
                bsplit(v0.z, h, l); ahi[2] = h; alo[2] = l;
                bsplit(v0.w, h, l); ahi[3] = h; alo[3] = l;
                bsplit(v1.x, h, l); ahi[4] = h; alo[4] = l;
                bsplit(v1.y, h, l); ahi[5] = h; alo[5] = l;
                bsplit(v1.z, h, l); ahi[6] = h; alo[6] = l;
                bsplit(v1.w, h, l); ahi[7] = h; alo[7] = l;
                acc[t] = __builtin_amdgcn_mfma_f32_16x16x32_bf16(ahi, bhi, acc[t], 0, 0, 0);
                acc[t] = __builtin_amdgcn_mfma_f32_16x16x32_bf16(ahi, blo, acc[t], 0, 0, 0);
                acc[t] = __builtin_amdgcn_mfma_f32_16x16x32_bf16(alo, bhi, acc[t], 0, 0, 0);
            }
        }
        __syncthreads();
    }

    // Epilogue (D: col=lane&15, row=4*(lane>>4)+reg; tile 6 -> rows 84..99)
    const float bcol = bias[ncol];
#pragma unroll
    for (int t = 0; t < 7; t++) {
        const int rbase = ((t < 6) ? t * 16 : 84) + q * 4;
#pragma unroll
        for (int r = 0; r < 4; r++) {
            const int row = rbase + r;
            if (t < 6 || row >= 96) {
                const float dn = A[row * ASTR + DINVC];
                const float v = acc[t][r];
                float o;
                if (FINAL) o = fmaxf(v * (1.0f / dn) + bcol, 0.f);
                else       o = fmaxf(v + bcol * dn, 0.f);
                A[swf(row, ncol)] = o;
            }
        }
    }
    __syncthreads();
}

__global__ __launch_bounds__(256, 4) void gnn_kernel(
    const float* __restrict__ feat,
    const int* __restrict__ src, const int* __restrict__ dst,
    const float* __restrict__ b1, const float* __restrict__ b2,
    const float* __restrict__ b3,
    const float* __restrict__ Wfc, const float* __restrict__ bfc,
    const short* __restrict__ wt, const short* __restrict__ aint,
    float* __restrict__ out)
{
    __shared__ __align__(16) float A[P * ASTR];   // 40,000 B
    const int g = blockIdx.x;
    const int tid = threadIdx.x;
    const int base = g * P;
    const int* dstg = dst + g * EPG;

    // ---- degree count (col DEGC, unswizzled meta) ----
    for (int i = tid; i < P; i += 256) *(int*)&A[i * ASTR + DEGC] = 0;
    __syncthreads();
    for (int e = tid; e < EPG; e += 256) {
        int d = dstg[e] - base;
        atomicAdd((int*)&A[d * ASTR + DEGC], 1);
    }
    __syncthreads();
    for (int i = tid; i < P; i += 256) {
        int dg = *(int*)&A[i * ASTR + DEGC];
        A[i * ASTR + DINVC] = rsqrtf((float)(dg > 1 ? dg : 1));
    }
    __syncthreads();

    // ---- feat load prescaled (Y = dinv*feat), granule-swizzled ----
    for (int i = tid; i < P * INF / 4; i += 256) {
        int n = i >> 2, fq = (i & 3) * 4;
        float4 v = *(const float4*)&feat[(size_t)base * INF + i * 4];
        float dn = A[n * ASTR + DINVC];
        v.x *= dn; v.y *= dn; v.z *= dn; v.w *= dn;
        *(float4*)&A[swf(n, fq)] = v;
    }
    __syncthreads();

    // ---- per-wave tile assignment + dinv preload ----
    const int lane = tid & 63, wv = tid >> 6, q = lane >> 4, n16 = lane & 15;
    const int rb0 = wv * 16;
    const int t2i = wv + 4;
    const int rb1 = (t2i >= 6) ? 84 : t2i * 16;
    const bool has2 = (wv < 3);
    f32x4 dv0, dv1;
#pragma unroll
    for (int r = 0; r < 4; r++) {
        dv0[r] = A[(rb0 + q * 4 + r) * ASTR + DINVC];
        dv1[r] = A[((has2 ? rb1 : rb0) + q * 4 + r) * ASTR + DINVC];
    }

    const short* aintg = aint + (size_t)g * AINT_SZ;
    const int arow0 = rb0 + n16;
    const int arow1 = (has2 ? rb1 : rb0) + n16;

    cheb_layer<INF, 0>(A, aintg, arow0, arow1, has2,
                       wt + L1HI, wt + L1LO, b1, tid, rb0, rb1, dv0, dv1);
    cheb_layer<HID, 0>(A, aintg, arow0, arow1, has2,
                       wt + L2HI, wt + L2LO, b2, tid, rb0, rb1, dv0, dv1);
    cheb_layer<HID, 1>(A, aintg, arow0, arow1, has2,
                       wt + L3HI, wt + L3LO, b3, tid, rb0, rb1, dv0, dv1);

    // ---- mean pool + FC (round-1 verbatim + swf) ----
    {
        const int l = tid & 63, w = tid >> 6;
        float s = 0.f;
        for (int n = w; n < P; n += 4) s += A[swf(n, l)];
        A[swf(l, T1OFF + w)] = s;
    }
    __syncthreads();
    if (tid < HID) {
        float hg = (A[swf(tid, T1OFF)] + A[swf(tid, T1OFF + 1)] +
                    A[swf(tid, T1OFF + 2)] + A[swf(tid, T1OFF + 3)]) * (1.0f / P);
        A[swf(tid, T1OFF + 4)] = hg;
    }
    __syncthreads();
    if (tid < NOUT) {
        float o = bfc[tid];
        for (int c = 0; c < HID; c++) o += A[swf(c, T1OFF + 4)] * Wfc[c * NOUT + tid];
        out[g * NOUT + tid] = o;
    }
}

extern "C" void kernel_launch(void* const* d_in, const int* in_sizes, int n_in,
                              void* d_out, int out_size, void* d_ws, size_t ws_size,
                              hipStream_t stream)
{
    const float* feat = (const float*)d_in[0];
    const int*   src  = (const int*)d_in[1];
    const int*   dst  = (const int*)d_in[2];
    const float* W1  = (const float*)d_in[5];
    const float* b1  = (const float*)d_in[6];
    const float* W2  = (const float*)d_in[7];
    const float* b2  = (const float*)d_in[8];
    const float* W3  = (const float*)d_in[9];
    const float* b3  = (const float*)d_in[10];
    const float* Wfc = (const float*)d_in[11];
    const float* bfc = (const float*)d_in[12];
    float* out = (float*)d_out;

    short* wt   = (short*)d_ws;                 // 122,880 B
    short* aint = wt + WT_SHORTS;               // + 25,600,000 B

    wprep<<<64, 256, 0, stream>>>(W1, W2, W3, wt);
    abuild<<<NGRAPH, 256, 0, stream>>>(src, dst, aint);
    gnn_kernel<<<NGRAPH, 256, 0, stream>>>(feat, src, dst,
                                           b1, b2, b3, Wfc, bfc, wt, aint, out);
}

// Round 10
// 159.096 us; speedup vs baseline: 2.1586x; 1.1164x over previous
//
#include <hip/hip_runtime.h>

#define NGRAPH 1000
#define P      100
#define EPG    1200
#define INF    16
#define HID    64
#define NOUT   5

// r28 = round-1 r19 RESTORED BYTE-IDENTICAL (session best: 161.7us total,
// gnn 82.8us, WRITE 47KB, VGPR 64 — the only codegen-clean configuration in
// 9 rounds). Eight failed variants established the empirical law:
//   * packed-u32 / v_perm / bit_cast fragment builds  -> 40-90MB scratch
//   * persistent cross-barrier short8 fragments       -> 40-93MB scratch
//   * dual bf16 planes                                -> 47MB scratch
//   * address-swizzle in the r19 frame (r27)          -> +23MB spill,
//     conflicts UNCHANGED (8.2e6 vs 8.1e6 — conflict model wrong)
// The raw-fp32-LDS + inline-bsplit + per-prop-adjacency-load structure is
// the codegen-stable optimum; do not perturb it.
// ONLY change vs round-1: wprep merged into abuild ("prep", one dispatch
// fewer; wprep work grid-strided across the full 1000-block grid). The gnn
// kernel and all its inputs are untouched.

#define ASTR   100
#define DINVC  64
#define DEGC   65
#define T1OFF  68
#define T2OFF  84

#define AINT_K   128
#define AINT_SZ  (P * AINT_K)     // 12800 shorts per graph

// wt table offsets (shorts). L1: RK=64 (48 real + 16 zero). L2/L3: RK=208.
#define RK1    64
#define RK2    208
#define L1HI   0
#define L1LO   4096
#define L2HI   8192
#define L2LO   21504
#define L3HI   34816
#define L3LO   48128
#define WT_SHORTS 61440

typedef short short8 __attribute__((ext_vector_type(8)));
typedef float f32x4  __attribute__((ext_vector_type(4)));

__device__ __forceinline__ void bsplit(float x, short& h, short& l) {
    unsigned u = __float_as_uint(x);
    h = (short)(u >> 16);
    float hf = __uint_as_float(u & 0xffff0000u);
    l = (short)(__float_as_uint(x - hf) >> 16);
}

// ---- merged pre-kernel: W split/transpose + per-graph adjacency build ----
__global__ __launch_bounds__(256) void prep(
    const float* __restrict__ W1, const float* __restrict__ W2,
    const float* __restrict__ W3, short* __restrict__ wt,
    const int* __restrict__ src, const int* __restrict__ dst,
    short* __restrict__ aint)
{
    const int tid = threadIdx.x;
    // -- wprep part (grid-strided over the whole grid; <=1 iter/thread) --
    {
        const int i0 = blockIdx.x * blockDim.x + tid;
        const int stride = gridDim.x * blockDim.x;
        for (int e = i0; e < HID * RK1; e += stride) {
            int c = e / RK1, r = e % RK1;
            float v = (r < 3 * INF) ? W1[r * HID + c] : 0.f;
            short h, l; bsplit(v, h, l);
            wt[L1HI + e] = h;
            wt[L1LO + e] = l;
        }
        for (int e = i0; e < HID * RK2; e += stride) {
            int c = e / RK2, r = e % RK2;
            float v2 = (r < 3 * HID) ? W2[r * HID + c] : 0.f;
            float v3 = (r < 3 * HID) ? W3[r * HID + c] : 0.f;
            short h, l;
            bsplit(v2, h, l); wt[L2HI + e] = h; wt[L2LO + e] = l;
            bsplit(v3, h, l); wt[L3HI + e] = h; wt[L3LO + e] = l;
        }
    }
    // -- abuild part (round-1 verbatim) --
    __shared__ unsigned int cnt[AINT_SZ / 2];     // 25,600 B
    const int g = blockIdx.x, base = g * P;
    for (int i = tid; i < AINT_SZ / 2; i += 256) cnt[i] = 0u;
    __syncthreads();
    const int* srcg = src + g * EPG;
    const int* dstg = dst + g * EPG;
    for (int e = tid; e < EPG; e += 256) {
        int s = srcg[e] - base;
        int d = dstg[e] - base;
        int idx = d * AINT_K + s;
        atomicAdd(&cnt[idx >> 1], 1u << ((idx & 1) * 16));
    }
    __syncthreads();
    unsigned int* outw = (unsigned int*)(aint + (size_t)g * AINT_SZ);
    for (int i = tid; i < AINT_SZ / 2; i += 256) {
        unsigned int u = cnt[i];
        unsigned int b0 = __float_as_uint((float)(u & 0xffffu)) >> 16;
        unsigned int b1 = __float_as_uint((float)(u >> 16)) >> 16;
        outw[i] = b0 | (b1 << 16);
    }
}

// ---- one dense propagation: dst slot = -d^2*(Aint@src)  (SECOND: -2d^2*.. - Y)
template <int SECOND>
__device__ __forceinline__ void dense_prop(
    float* __restrict__ A, const short* __restrict__ aintg,
    int arow0, int arow1, bool has2,
    int srcoff, int dstoff, int ycol,
    int rb0, int rb1, f32x4 dv0, f32x4 dv1, int lane)
{
    const int n16 = lane & 15;
    const int q   = lane >> 4;
    const int kq  = q * 8;
    f32x4 p0, p1;
    p0[0]=0.f; p0[1]=0.f; p0[2]=0.f; p0[3]=0.f;
    p1[0]=0.f; p1[1]=0.f; p1[2]=0.f; p1[3]=0.f;
#pragma unroll
    for (int k = 0; k < 4; k++) {
        const short8 a0 = *(const short8*)&aintg[arow0 * AINT_K + k * 32 + kq];
        const short8 a1 = *(const short8*)&aintg[arow1 * AINT_K + k * 32 + kq];
        short8 bhi, blo; short h, l;
#pragma unroll
        for (int j = 0; j < 8; j++) {
            int row = k * 32 + kq + j;
            if (k == 3) row = (row < P) ? row : 0;   // Aint cols >=100 are 0
            float x = A[row * ASTR + srcoff + n16];
            bsplit(x, h, l); bhi[j] = h; blo[j] = l;
        }
        p0 = __builtin_amdgcn_mfma_f32_16x16x32_bf16(a0, bhi, p0, 0, 0, 0);
        p0 = __builtin_amdgcn_mfma_f32_16x16x32_bf16(a0, blo, p0, 0, 0, 0);
        if (has2) {
            p1 = __builtin_amdgcn_mfma_f32_16x16x32_bf16(a1, bhi, p1, 0, 0, 0);
            p1 = __builtin_amdgcn_mfma_f32_16x16x32_bf16(a1, blo, p1, 0, 0, 0);
        }
    }
#pragma unroll
    for (int r = 0; r < 4; r++) {
        const int row = rb0 + q * 4 + r;
        const float d2 = dv0[r] * dv0[r];
        float o;
        if (SECOND) o = -2.f * d2 * p0[r] - A[row * ASTR + ycol];
        else        o = -d2 * p0[r];
        A[row * ASTR + dstoff + n16] = o;
    }
    if (has2) {
#pragma unroll
        for (int r = 0; r < 4; r++) {
            const int row = rb1 + q * 4 + r;
            if (rb1 != 84 || row >= 96) {            // tile-6 overlap guard
                const float d2 = dv1[r] * dv1[r];
                float o;
                if (SECOND) o = -2.f * d2 * p1[r] - A[row * ASTR + ycol];
                else        o = -d2 * p1[r];
                A[row * ASTR + dstoff + n16] = o;
            }
        }
    }
}

// ---- one ChebConv layer ----
template <int F, int FINAL>
__device__ __forceinline__ void cheb_layer(
    float* __restrict__ A, const short* __restrict__ aintg,
    const short* __restrict__ whi, const short* __restrict__ wlo,
    const float* __restrict__ bias,
    int tid, int rb0, int rb1, bool has2, f32x4 dv0, f32x4 dv1)
{
    const int RK   = 3 * F + 16;
    const int lane = tid & 63;
    const int wv   = tid >> 6;
    const int n16  = lane & 15;
    const int q    = lane >> 4;
    const int ncol = (wv << 4) + n16;

    const int arow0 = rb0 + n16;
    const int arow1 = (has2 ? rb1 : rb0) + n16;

    f32x4 acc[7];
#pragma unroll
    for (int t = 0; t < 7; t++) { acc[t][0]=0.f; acc[t][1]=0.f; acc[t][2]=0.f; acc[t][3]=0.f; }

    for (int cb = 0; cb < F; cb += 16) {
        dense_prop<0>(A, aintg, arow0, arow1, has2, cb,    T1OFF, 0,
                      rb0, rb1, dv0, dv1, lane);
        __syncthreads();
        dense_prop<1>(A, aintg, arow0, arow1, has2, T1OFF, T2OFF, cb + n16,
                      rb0, rb1, dv0, dv1, lane);
        __syncthreads();

        // W partial: chunk K-layout [Y16 | T1_16 | T2_16 | zero16], 2 K-steps
#pragma unroll
        for (int ks = 0; ks < 2; ks++) {
            int wr, aoff;
            if (ks == 0) {
                wr   = (q == 0) ? cb : (q == 1) ? cb + 8 : (q == 2) ? F + cb : F + cb + 8;
                aoff = (q == 0) ? cb : (q == 1) ? cb + 8 : (q == 2) ? T1OFF  : T1OFF + 8;
            } else {
                wr   = (q == 0) ? 2*F + cb : (q == 1) ? 2*F + cb + 8 : (q == 2) ? 3*F : 3*F + 8;
                aoff = (q == 0) ? T2OFF    : (q == 1) ? T2OFF + 8    : (q == 2) ? T1OFF : T1OFF + 8;
            }
            const short8 bhi = *(const short8*)&whi[ncol * RK + wr];
            const short8 blo = *(const short8*)&wlo[ncol * RK + wr];
#pragma unroll
            for (int t = 0; t < 7; t++) {
                const int row = ((t < 6) ? t * 16 : 84) + n16;
                const float* xp = &A[row * ASTR + aoff];
                const float4 v0 = *(const float4*)xp;
                const float4 v1 = *(const float4*)(xp + 4);
                short8 ahi, alo; short h, l;
                bsplit(v0.x, h, l); ahi[0] = h; alo[0] = l;
                bsplit(v0.y, h, l); ahi[1] = h; alo[1] = l;
                bsplit(v0.z, h, l); ahi[2] = h; alo[2] = l;
                bsplit(v0.w, h, l); ahi[3] = h; alo[3] = l;
                bsplit(v1.x, h, l); ahi[4] = h; alo[4] = l;
                bsplit(v1.y, h, l); ahi[5] = h; alo[5] = l;
                bsplit(v1.z, h, l); ahi[6] = h; alo[6] = l;
                bsplit(v1.w, h, l); ahi[7] = h; alo[7] = l;
                acc[t] = __builtin_amdgcn_mfma_f32_16x16x32_bf16(ahi, bhi, acc[t], 0, 0, 0);
                acc[t] = __builtin_amdgcn_mfma_f32_16x16x32_bf16(ahi, blo, acc[t], 0, 0, 0);
                acc[t] = __builtin_amdgcn_mfma_f32_16x16x32_bf16(alo, bhi, acc[t], 0, 0, 0);
            }
        }
        __syncthreads();
    }

    // Epilogue (D: col=lane&15, row=4*(lane>>4)+reg; tile 6 -> rows 84..99)
    const float bcol = bias[ncol];
#pragma unroll
    for (int t = 0; t < 7; t++) {
        const int rbase = ((t < 6) ? t * 16 : 84) + q * 4;
#pragma unroll
        for (int r = 0; r < 4; r++) {
            const int row = rbase + r;
            if (t < 6 || row >= 96) {
                const float dn = A[row * ASTR + DINVC];
                const float v = acc[t][r];
                float o;
                if (FINAL) o = fmaxf(v * (1.0f / dn) + bcol, 0.f);
                else       o = fmaxf(v + bcol * dn, 0.f);
                A[row * ASTR + ncol] = o;
            }
        }
    }
    __syncthreads();
}

__global__ __launch_bounds__(256, 4) void gnn_kernel(
    const float* __restrict__ feat,
    const int* __restrict__ src, const int* __restrict__ dst,
    const float* __restrict__ b1, const float* __restrict__ b2,
    const float* __restrict__ b3,
    const float* __restrict__ Wfc, const float* __restrict__ bfc,
    const short* __restrict__ wt, const short* __restrict__ aint,
    float* __restrict__ out)
{
    __shared__ __align__(16) float A[P * ASTR];   // 40,000 B
    const int g = blockIdx.x;
    const int tid = threadIdx.x;
    const int base = g * P;
    const int* dstg = dst + g * EPG;

    // ---- degree count (col DEGC) ----
    for (int i = tid; i < P; i += 256) *(int*)&A[i * ASTR + DEGC] = 0;
    __syncthreads();
    for (int e = tid; e < EPG; e += 256) {
        int d = dstg[e] - base;
        atomicAdd((int*)&A[d * ASTR + DEGC], 1);
    }
    __syncthreads();
    for (int i = tid; i < P; i += 256) {
        int dg = *(int*)&A[i * ASTR + DEGC];
        A[i * ASTR + DINVC] = rsqrtf((float)(dg > 1 ? dg : 1));
    }
    __syncthreads();

    // ---- feat load prescaled (A = dinv*feat) ----
    for (int i = tid; i < P * INF / 4; i += 256) {
        int n = i >> 2, fq = (i & 3) * 4;
        float4 v = *(const float4*)&feat[(size_t)base * INF + i * 4];
        float dn = A[n * ASTR + DINVC];
        v.x *= dn; v.y *= dn; v.z *= dn; v.w *= dn;
        *(float4*)&A[n * ASTR + fq] = v;
    }
    __syncthreads();

    // ---- per-wave tile assignment + dinv preload for prop epilogues ----
    const int lane = tid & 63, wv = tid >> 6, q = lane >> 4;
    const int rb0 = wv * 16;
    const int t2i = wv + 4;
    const int rb1 = (t2i >= 6) ? 84 : t2i * 16;
    const bool has2 = (wv < 3);
    f32x4 dv0, dv1;
#pragma unroll
    for (int r = 0; r < 4; r++) {
        dv0[r] = A[(rb0 + q * 4 + r) * ASTR + DINVC];
        dv1[r] = A[((has2 ? rb1 : rb0) + q * 4 + r) * ASTR + DINVC];
    }

    const short* aintg = aint + (size_t)g * AINT_SZ;
    cheb_layer<INF, 0>(A, aintg, wt + L1HI, wt + L1LO, b1, tid, rb0, rb1, has2, dv0, dv1);
    cheb_layer<HID, 0>(A, aintg, wt + L2HI, wt + L2LO, b2, tid, rb0, rb1, has2, dv0, dv1);
    cheb_layer<HID, 1>(A, aintg, wt + L3HI, wt + L3LO, b3, tid, rb0, rb1, has2, dv0, dv1);

    // ---- mean pool + FC (psum in the now-free T1/T2 slots) ----
    {
        const int l2 = tid & 63, w = tid >> 6;
        float s = 0.f;
        for (int n = w; n < P; n += 4) s += A[n * ASTR + l2];
        A[l2 * ASTR + T1OFF + w] = s;
    }
    __syncthreads();
    if (tid < HID) {
        float hg = (A[tid * ASTR + T1OFF] + A[tid * ASTR + T1OFF + 1] +
                    A[tid * ASTR + T1OFF + 2] + A[tid * ASTR + T1OFF + 3]) * (1.0f / P);
        A[tid * ASTR + T1OFF + 4] = hg;
    }
    __syncthreads();
    if (tid < NOUT) {
        float o = bfc[tid];
        for (int c = 0; c < HID; c++) o += A[c * ASTR + T1OFF + 4] * Wfc[c * NOUT + tid];
        out[g * NOUT + tid] = o;
    }
}

extern "C" void kernel_launch(void* const* d_in, const int* in_sizes, int n_in,
                              void* d_out, int out_size, void* d_ws, size_t ws_size,
                              hipStream_t stream)
{
    const float* feat = (const float*)d_in[0];
    const int*   src  = (const int*)d_in[1];
    const int*   dst  = (const int*)d_in[2];
    const float* W1  = (const float*)d_in[5];
    const float* b1  = (const float*)d_in[6];
    const float* W2  = (const float*)d_in[7];
    const float* b2  = (const float*)d_in[8];
    const float* W3  = (const float*)d_in[9];
    const float* b3  = (const float*)d_in[10];
    const float* Wfc = (const float*)d_in[11];
    const float* bfc = (const float*)d_in[12];
    float* out = (float*)d_out;

    short* wt   = (short*)d_ws;                 // 122,880 B
    short* aint = wt + WT_SHORTS;               // + 25,600,000 B

    prep<<<NGRAPH, 256, 0, stream>>>(W1, W2, W3, wt, src, dst, aint);
    gnn_kernel<<<NGRAPH, 256, 0, stream>>>(feat, src, dst,
                                           b1, b2, b3, Wfc, bfc, wt, aint, out);
}